// Round 6
// baseline (204.796 us; speedup 1.0000x reference)
//
#include <hip/hip_runtime.h>
#include <math.h>

#define B 1024
#define D 128
#define TDIM 1
#define NT 256

constexpr float THR   = 0.05f;
constexpr float LAM1f = 1.0f;
constexpr float LAM2f = 0.5f;
constexpr float EPSf  = 1e-8f;
constexpr float QS    = 16777216.0f;     // 2^24 fixed-point scale
constexpr double QI   = 1.0 / 16777216.0;

typedef unsigned long long u64;

// finalize column mean/std (ddof=1) from fixed-point sums (deterministic)
__device__ __forceinline__ void col_ms(const u64* csum, const u64* csq, int c,
                                       float& m_c, float& s_c) {
  double sum  = (double)(long long)csum[c] * QI;
  double ssq  = (double)(long long)csq[c]  * QI;
  double mean = sum * (1.0 / 1024.0);
  double var  = (ssq - sum * mean) * (1.0 / 1023.0);
  float sd = (float)sqrt(var > 0.0 ? var : 0.0);
  if (sd < 1e-6f) sd = 1e-6f;
  m_c = (float)mean; s_c = sd;
}

struct SelOut { unsigned total, bucket, rem; };

// cooperative 256-thread radix-select over a histogram level (pure integer
// math on identical global data -> bit-identical in every block)
__device__ SelOut block_select(const unsigned* __restrict__ h, int nb, unsigned kk_in) {
  int t = threadIdx.x;
  const int per = nb >> 8;                 // 8 (nb=2048) or 4 (nb=1024)
  unsigned local[8];
  unsigned lsum = 0;
#pragma unroll
  for (int q = 0; q < 8; ++q) {
    unsigned v = (q < per) ? h[t * per + q] : 0u;
    local[q] = v; lsum += v;
  }
  unsigned incl = lsum;
#pragma unroll
  for (int o = 1; o < 64; o <<= 1) {
    unsigned nbr = __shfl_up(incl, o, 64);
    if ((t & 63) >= o) incl += nbr;
  }
  __shared__ unsigned sel_wsum[4];
  __shared__ unsigned sel_res[3];
  if ((t & 63) == 63) sel_wsum[t >> 6] = incl;
  __syncthreads();
  unsigned wpre = 0;
  for (int wv = 0; wv < (t >> 6); ++wv) wpre += sel_wsum[wv];
  incl += wpre;
  unsigned excl = incl - lsum;
  if (t == 255) sel_res[0] = incl;
  __syncthreads();
  unsigned total = sel_res[0];
  unsigned kk = (kk_in == 0xFFFFFFFFu) ? ((total ? total - 1u : 0u) >> 1) : kk_in;
  if (total && kk >= excl && kk < incl) {   // exactly one thread
    unsigned cum = excl;
    for (int q = 0; q < per; ++q) {
      if (cum + local[q] > kk) { sel_res[1] = (unsigned)(t * per + q); sel_res[2] = kk - cum; break; }
      cum += local[q];
    }
  }
  __syncthreads();
  SelOut o; o.total = total; o.bucket = sel_res[1]; o.rem = sel_res[2];
  return o;
}

// ---- K0: zero hist/cursor/fixedpoint region + gather x[:,TDIM] ----
__global__ void __launch_bounds__(NT) k0_init(const float* __restrict__ x,
                                              unsigned* __restrict__ zb,
                                              float* __restrict__ xcol1) {
  int bid = blockIdx.x, t = threadIdx.x;
  if (bid < 8) {
    for (int idx = bid * NT + t; idx < 5648; idx += 8 * NT) zb[idx] = 0u;
  } else {
    int i = (bid - 8) * NT + t;
    if (i < B) xcol1[i] = x[i * D + TDIM];
  }
}

// ---- K1: fixed-point column sums (blocks 0..63) ||
//          per-row ballot -> keys + hist level 0 (blocks 64..1087) ----
__global__ void __launch_bounds__(NT) k1_colsum_keys(const float* __restrict__ x,
                                                     const float* __restrict__ y,
                                                     const float* __restrict__ xcol1,
                                                     u64* __restrict__ csum,
                                                     u64* __restrict__ csq,
                                                     unsigned* __restrict__ cursor,
                                                     unsigned* __restrict__ keys,
                                                     unsigned* __restrict__ h0) {
  int bid = blockIdx.x, t = threadIdx.x;
  if (bid < 64) {
    int c = t & 127, h = t >> 7;
    int rbase = bid * 16 + h * 8;
    long long qs = 0, qq = 0;
#pragma unroll
    for (int r = 0; r < 8; ++r) {
      float v = x[(rbase + r) * D + c];
      qs += llrintf(v * QS);
      qq += llrintf(v * v * QS);
    }
    atomicAdd(&csum[c], (u64)qs);
    atomicAdd(&csq[c],  (u64)qq);
    return;
  }
  int i = bid - 64;                         // row 0..1023
  __shared__ unsigned keybuf[B];
  __shared__ unsigned wcnt[4];
  __shared__ unsigned start_sh;
  float yi = y[i], xi1 = xcol1[i];
  unsigned base = 0;
  int lane = t & 63, wv = t >> 6;
  for (int rnd = 0; rnd < 4; ++rnd) {
    int j = rnd * NT + t;
    bool ok = (j != i) && (fabsf(yi - y[j]) <= THR);
    float dxr = xi1 - xcol1[j];
    unsigned key = __float_as_uint(dxr * dxr);
    unsigned long long mk = __ballot(ok);
    if (lane == 0) wcnt[wv] = (unsigned)__popcll(mk);
    __syncthreads();
    unsigned pre = base;
    for (int w2 = 0; w2 < wv; ++w2) pre += wcnt[w2];
    if (ok) {
      unsigned mypos = (unsigned)__popcll(mk & ((1ull << lane) - 1ull));
      keybuf[pre + mypos] = key;
    }
    base += wcnt[0] + wcnt[1] + wcnt[2] + wcnt[3];
    __syncthreads();
  }
  unsigned cnt = base;
  if (t == 0) start_sh = atomicAdd(cursor, cnt);
  __syncthreads();
  unsigned st = start_sh;
  for (unsigned q = t; q < cnt; q += NT) {
    unsigned k = keybuf[q];
    keys[st + q] = k;
    atomicAdd(&h0[k >> 21], 1u);
  }
}

// ---- K2: hist level 1 (blocks 0..63, stream keys) ||
//          normalize rows -> xn, z2, r2o (blocks 64..575, 2 rows each) ----
__global__ void __launch_bounds__(NT) k2_h1_norm(const float* __restrict__ x,
                                                 const unsigned* __restrict__ keys,
                                                 const unsigned* __restrict__ cursor,
                                                 const unsigned* __restrict__ h0,
                                                 unsigned* __restrict__ h1,
                                                 const u64* __restrict__ csum,
                                                 const u64* __restrict__ csq,
                                                 float* __restrict__ xn,
                                                 float* __restrict__ z2,
                                                 float* __restrict__ r2o) {
  int bid = blockIdx.x, t = threadIdx.x;
  if (bid < 64) {
    SelOut s0 = block_select(h0, 2048, 0xFFFFFFFFu);
    if (s0.total == 0) return;
    unsigned np = cursor[0];
    for (unsigned idx = bid * NT + t; idx < np; idx += 64 * NT) {
      unsigned bits = keys[idx];
      if ((bits >> 21) == s0.bucket) atomicAdd(&h1[(bits >> 10) & 0x7FFu], 1u);
    }
    return;
  }
  int pr = bid - 64;                        // 0..511, two rows each
  int half = t >> 7, c = t & 127;
  int row = 2 * pr + half;
  float m_c, s_c;
  col_ms(csum, csq, c, m_c, s_c);
  float v = (x[row * D + c] - m_c) / s_c;
  xn[row * D + c] = v;
  if (c == TDIM) z2[row] = v;
  __shared__ float red[NT];
  red[t] = (c != TDIM) ? v * v : 0.f;
  __syncthreads();
  for (int o = 64; o > 0; o >>= 1) {
    if ((t & 127) < o) red[t] += red[t + o];
    __syncthreads();
  }
  if ((t & 127) == 0) r2o[row] = red[t];
}

// ---- K3: hist level 2 (stream keys) ----
__global__ void __launch_bounds__(NT) k3_h2(const unsigned* __restrict__ keys,
                                            const unsigned* __restrict__ cursor,
                                            const unsigned* __restrict__ h0,
                                            const unsigned* __restrict__ h1,
                                            unsigned* __restrict__ h2) {
  int bid = blockIdx.x, t = threadIdx.x;
  SelOut s0 = block_select(h0, 2048, 0xFFFFFFFFu);
  if (s0.total == 0) return;
  SelOut s1 = block_select(h1, 2048, s0.rem);
  unsigned pref = (s0.bucket << 11) | s1.bucket;
  unsigned np = cursor[0];
  for (unsigned idx = bid * NT + t; idx < np; idx += 64 * NT) {
    unsigned bits = keys[idx];
    if ((bits >> 10) == pref) atomicAdd(&h2[bits & 0x3FFu], 1u);
  }
}

// ---- K4: pairwise pass (redundant selects; ballot-compacted j list) ----
__global__ void __launch_bounds__(NT) k4_pair(const float* __restrict__ y,
                                              const float* __restrict__ z2,
                                              const float* __restrict__ r2o,
                                              const float* __restrict__ xn,
                                              const unsigned* __restrict__ h0,
                                              const unsigned* __restrict__ h1,
                                              const unsigned* __restrict__ h2,
                                              const u64* __restrict__ csum,
                                              const u64* __restrict__ csq,
                                              float* __restrict__ loss_i,
                                              unsigned* __restrict__ haspos_i) {
  int t = threadIdx.x;
  int i = blockIdx.x;

  SelOut s0 = block_select(h0, 2048, 0xFFFFFFFFu);
  SelOut s1; s1.bucket = 0; s1.rem = 0;
  SelOut s2; s2.bucket = 0;
  if (s0.total) {
    s1 = block_select(h1, 2048, s0.rem);
    s2 = block_select(h2, 1024, s1.rem);
  }
  __shared__ float tb;
  if (t == 0) {
    if (s0.total) {
      unsigned bits = (s0.bucket << 21) | (s1.bucket << 10) | s2.bucket;
      float mc, sc; col_ms(csum, csq, TDIM, mc, sc);
      float inv = 1.0f / sc;
      tb = fmaxf(__uint_as_float(bits) * inv * inv, 1e-6f);
    } else tb = 2.0f;
  }
  __syncthreads();
  const float invT = 1.0f / tb;

  __shared__ float xi_sh[D];
  if (t < D) xi_sh[t] = xn[i * D + t];

  float yi = y[i], zi = z2[i], ri = r2o[i];

  // den1 over ALL j (j==i contributes exp(0)=1 exactly; removed after reduce)
  float4 zz = *(const float4*)(z2 + t * 4);
  float e0 = zi - zz.x, e1 = zi - zz.y, e2 = zi - zz.z, e3 = zi - zz.w;
  float den1 = __expf(-e0 * e0 * invT) + __expf(-e1 * e1 * invT)
             + __expf(-e2 * e2 * invT) + __expf(-e3 * e3 * invT);

  // deterministic ballot-compaction of same-age neighbors
  __shared__ unsigned short jlist[B];
  __shared__ unsigned wcnt_sh[4];
  unsigned base = 0;
  int lane = t & 63, wv = t >> 6;
  for (int rnd = 0; rnd < 4; ++rnd) {
    int j = rnd * NT + t;
    bool ok = (j != i) && (fabsf(yi - y[j]) <= THR);
    unsigned long long mk = __ballot(ok);
    if (lane == 0) wcnt_sh[wv] = (unsigned)__popcll(mk);
    __syncthreads();
    unsigned pre = base;
    for (int w2 = 0; w2 < wv; ++w2) pre += wcnt_sh[w2];
    if (ok) {
      unsigned mypos = (unsigned)__popcll(mk & ((1ull << lane) - 1ull));
      jlist[pre + mypos] = (unsigned short)j;
    }
    base += wcnt_sh[0] + wcnt_sh[1] + wcnt_sh[2] + wcnt_sh[3];
    __syncthreads();
  }
  unsigned cnt = base;   // block-uniform, deterministic (sorted by j)

  float num = 0.f, den2 = 0.f;
  for (unsigned q = t; q < cnt; q += NT) {
    int j = jlist[q];
    float zj = z2[j];
    float dz = zi - zj;
    num += __expf(-dz * dz * invT);
    const float* xj = xn + j * D;
    float dot = 0.f;
#pragma unroll
    for (int d = 0; d < D; d += 4) {
      float4 a  = *(const float4*)(xi_sh + d);
      float4 bb = *(const float4*)(xj + d);
      dot += a.x * bb.x + a.y * bb.y + a.z * bb.z + a.w * bb.w;
    }
    float dot_o = dot - xi_sh[TDIM] * xj[TDIM];
    float sq = fmaxf((ri + r2o[j] - 2.f * dot_o) * (1.0f / 127.0f), 0.f);
    den2 += __expf(-sq * invT);
  }

  __shared__ float rn[NT], r1[NT], r2s[NT];
  rn[t] = num; r1[t] = den1; r2s[t] = den2;
  __syncthreads();
  for (int o = 128; o > 0; o >>= 1) {
    if (t < o) { rn[t] += rn[t + o]; r1[t] += r1[t + o]; r2s[t] += r2s[t + o]; }
    __syncthreads();
  }
  if (t == 0) {
    float den1t = r1[0] - 1.0f;               // remove j==i term
    float denom = LAM1f * den1t + LAM2f * r2s[0] + EPSf;
    float frac = fminf(fmaxf(rn[0] / denom, 1e-12f), 1.0f - 1e-7f);
    loss_i[i]   = (cnt > 0) ? -__logf(frac) : 0.f;
    haspos_i[i] = (cnt > 0) ? 1u : 0u;
  }
}

// ---- K5: final deterministic reduction to scalar loss ----
__global__ void __launch_bounds__(NT) k5_final(const float* __restrict__ loss_i,
                                               const unsigned* __restrict__ haspos_i,
                                               float* __restrict__ out) {
  __shared__ float rs[NT];
  __shared__ unsigned rcnt[NT];
  int t = threadIdx.x;
  float sv = 0.f;
  unsigned c = 0;
  for (int i = t; i < B; i += NT) { sv += loss_i[i]; c += haspos_i[i]; }
  rs[t] = sv; rcnt[t] = c;
  __syncthreads();
  for (int o = 128; o > 0; o >>= 1) {
    if (t < o) { rs[t] += rs[t + o]; rcnt[t] += rcnt[t + o]; }
    __syncthreads();
  }
  if (t == 0) out[0] = (rcnt[0] > 0) ? rs[0] / (float)rcnt[0] : 0.f;
}

extern "C" void kernel_launch(void* const* d_in, const int* in_sizes, int n_in,
                              void* d_out, int out_size, void* d_ws, size_t ws_size,
                              hipStream_t stream) {
  const float* x = (const float*)d_in[0];   // (1024,128) f32
  const float* y = (const float*)d_in[1];   // (1024,)    f32
  float* out = (float*)d_out;               // scalar f32

  char* w = (char*)d_ws;
  unsigned* zb     = (unsigned*)w;                 // zeroed region: u32[5648]
  unsigned* h0     = zb;                           // 2048
  unsigned* h1     = zb + 2048;                    // 2048
  unsigned* h2     = zb + 4096;                    // 1024
  unsigned* cursor = zb + 5120;                    // 1 (+15 pad)
  u64* csum        = (u64*)(w + 20544);            // 128 x u64
  u64* csq         = (u64*)(w + 21568);            // 128 x u64 (zero ends 22592)
  float* xcol1     = (float*)(w + 22592);          // 4 KB
  float* z2        = (float*)(w + 26688);          // 4 KB
  float* r2o       = (float*)(w + 30784);          // 4 KB
  float* loss_i    = (float*)(w + 34880);          // 4 KB
  unsigned* haspos = (unsigned*)(w + 38976);       // 4 KB
  float* xn        = (float*)(w + 43072);          // 512 KB
  unsigned* keys   = (unsigned*)(w + 567360);      // 4 MB (worst case 1024*1023)

  k0_init<<<12, NT, 0, stream>>>(x, zb, xcol1);
  k1_colsum_keys<<<64 + B, NT, 0, stream>>>(x, y, xcol1, csum, csq,
                                            cursor, keys, h0);
  k2_h1_norm<<<64 + B / 2, NT, 0, stream>>>(x, keys, cursor, h0, h1,
                                            csum, csq, xn, z2, r2o);
  k3_h2<<<64, NT, 0, stream>>>(keys, cursor, h0, h1, h2);
  k4_pair<<<B, NT, 0, stream>>>(y, z2, r2o, xn, h0, h1, h2, csum, csq,
                                loss_i, haspos);
  k5_final<<<1, NT, 0, stream>>>(loss_i, haspos, out);
}

// Round 7
// 62.639 us; speedup vs baseline: 3.2695x; 3.2695x over previous
//
#include <hip/hip_runtime.h>
#include <math.h>

#define B 1024
#define D 128
#define TDIM 1
#define NT 256

constexpr float THR   = 0.05f;
constexpr float LAM1f = 1.0f;
constexpr float LAM2f = 0.5f;
constexpr float EPSf  = 1e-8f;
constexpr float QS    = 16777216.0f;     // 2^24 fixed-point scale
constexpr double QI   = 1.0 / 16777216.0;

typedef unsigned long long u64;

// finalize column mean/std (ddof=1) from fixed-point sums (deterministic)
__device__ __forceinline__ void col_ms(const u64* csum, const u64* csq, int c,
                                       float& m_c, float& s_c) {
  double sum  = (double)(long long)csum[c] * QI;
  double ssq  = (double)(long long)csq[c]  * QI;
  double mean = sum * (1.0 / 1024.0);
  double var  = (ssq - sum * mean) * (1.0 / 1023.0);
  float sd = (float)sqrt(var > 0.0 ? var : 0.0);
  if (sd < 1e-6f) sd = 1e-6f;
  m_c = (float)mean; s_c = sd;
}

struct SelOut { unsigned total, bucket, rem; };

// cooperative 256-thread radix-select over a histogram level (pure integer
// math on identical global data -> bit-identical in every block)
__device__ SelOut block_select(const unsigned* __restrict__ h, int nb, unsigned kk_in) {
  int t = threadIdx.x;
  const int per = nb >> 8;                 // 8 (nb=2048) or 4 (nb=1024)
  unsigned local[8];
  unsigned lsum = 0;
#pragma unroll
  for (int q = 0; q < 8; ++q) {
    unsigned v = (q < per) ? h[t * per + q] : 0u;
    local[q] = v; lsum += v;
  }
  unsigned incl = lsum;
#pragma unroll
  for (int o = 1; o < 64; o <<= 1) {
    unsigned nbr = __shfl_up(incl, o, 64);
    if ((t & 63) >= o) incl += nbr;
  }
  __shared__ unsigned sel_wsum[4];
  __shared__ unsigned sel_res[3];
  if ((t & 63) == 63) sel_wsum[t >> 6] = incl;
  __syncthreads();
  unsigned wpre = 0;
  for (int wv = 0; wv < (t >> 6); ++wv) wpre += sel_wsum[wv];
  incl += wpre;
  unsigned excl = incl - lsum;
  if (t == 255) sel_res[0] = incl;
  __syncthreads();
  unsigned total = sel_res[0];
  unsigned kk = (kk_in == 0xFFFFFFFFu) ? ((total ? total - 1u : 0u) >> 1) : kk_in;
  if (total && kk >= excl && kk < incl) {   // exactly one thread
    unsigned cum = excl;
    for (int q = 0; q < per; ++q) {
      if (cum + local[q] > kk) { sel_res[1] = (unsigned)(t * per + q); sel_res[2] = kk - cum; break; }
      cum += local[q];
    }
  }
  __syncthreads();
  SelOut o; o.total = total; o.bucket = sel_res[1]; o.rem = sel_res[2];
  return o;
}

// ---- K0: zero hist/cursor/fixedpoint region + gather x[:,TDIM] ----
__global__ void __launch_bounds__(NT) k0_init(const float* __restrict__ x,
                                              unsigned* __restrict__ zb,
                                              float* __restrict__ xcol1) {
  int bid = blockIdx.x, t = threadIdx.x;
  if (bid < 8) {
    for (int idx = bid * NT + t; idx < 5648; idx += 8 * NT) zb[idx] = 0u;
  } else {
    int i = (bid - 8) * NT + t;
    if (i < B) xcol1[i] = x[i * D + TDIM];
  }
}

// ---- K1: fixed-point column sums (blocks 0..63) ||
//          4-rows-per-block ballot -> keys (global, coalesced) + LDS hist0
//          (blocks 64..319) ----
__global__ void __launch_bounds__(NT) k1_colsum_keys(const float* __restrict__ x,
                                                     const float* __restrict__ y,
                                                     const float* __restrict__ xcol1,
                                                     u64* __restrict__ csum,
                                                     u64* __restrict__ csq,
                                                     unsigned* __restrict__ cursor,
                                                     unsigned* __restrict__ keys,
                                                     unsigned* __restrict__ h0) {
  int bid = blockIdx.x, t = threadIdx.x;
  if (bid < 64) {
    int c = t & 127, h = t >> 7;
    int rbase = bid * 16 + h * 8;
    long long qs = 0, qq = 0;
#pragma unroll
    for (int r = 0; r < 8; ++r) {
      float v = x[(rbase + r) * D + c];
      qs += llrintf(v * QS);
      qq += llrintf(v * v * QS);
    }
    atomicAdd(&csum[c], (u64)qs);
    atomicAdd(&csq[c],  (u64)qq);
    return;
  }
  int rb = bid - 64;                        // 0..255, four rows each
  __shared__ unsigned keybuf[B];
  __shared__ unsigned lh[2048];
  __shared__ unsigned wcnt[4];
  __shared__ unsigned start_sh;
  for (int q = t; q < 2048; q += NT) lh[q] = 0;
  int lane = t & 63, wv = t >> 6;
  for (int rr = 0; rr < 4; ++rr) {
    int i = rb * 4 + rr;
    float yi = y[i], xi1 = xcol1[i];
    unsigned base = 0;
    __syncthreads();                        // lh init / keybuf reuse
    for (int rnd = 0; rnd < 4; ++rnd) {
      int j = rnd * NT + t;
      bool ok = (j != i) && (fabsf(yi - y[j]) <= THR);
      float dxr = xi1 - xcol1[j];
      unsigned key = __float_as_uint(dxr * dxr);
      unsigned long long mk = __ballot(ok);
      if (lane == 0) wcnt[wv] = (unsigned)__popcll(mk);
      __syncthreads();
      unsigned pre = base;
      for (int w2 = 0; w2 < wv; ++w2) pre += wcnt[w2];
      if (ok) {
        unsigned mypos = (unsigned)__popcll(mk & ((1ull << lane) - 1ull));
        keybuf[pre + mypos] = key;
      }
      base += wcnt[0] + wcnt[1] + wcnt[2] + wcnt[3];
      __syncthreads();
    }
    unsigned cnt = base;
    if (t == 0) start_sh = atomicAdd(cursor, cnt);
    __syncthreads();
    unsigned st = start_sh;
    for (unsigned q = t; q < cnt; q += NT) {
      unsigned k = keybuf[q];
      keys[st + q] = k;                     // coalesced
      atomicAdd(&lh[k >> 21], 1u);          // LDS atomic
    }
  }
  __syncthreads();
  for (int q = t; q < 2048; q += NT) {
    unsigned c = lh[q];
    if (c) atomicAdd(&h0[q], c);            // ~80 nonzero buckets/block
  }
}

// ---- K2: hist level 1 (blocks 0..63, stream keys via LDS hist) ||
//          normalize rows -> xn, z2, r2o (blocks 64..575, 2 rows each) ----
__global__ void __launch_bounds__(NT) k2_h1_norm(const float* __restrict__ x,
                                                 const unsigned* __restrict__ keys,
                                                 const unsigned* __restrict__ cursor,
                                                 const unsigned* __restrict__ h0,
                                                 unsigned* __restrict__ h1,
                                                 const u64* __restrict__ csum,
                                                 const u64* __restrict__ csq,
                                                 float* __restrict__ xn,
                                                 float* __restrict__ z2,
                                                 float* __restrict__ r2o) {
  int bid = blockIdx.x, t = threadIdx.x;
  if (bid < 64) {
    SelOut s0 = block_select(h0, 2048, 0xFFFFFFFFu);
    if (s0.total == 0) return;
    __shared__ unsigned lh[2048];
    for (int q = t; q < 2048; q += NT) lh[q] = 0;
    __syncthreads();
    unsigned np = cursor[0];
    for (unsigned idx = bid * NT + t; idx < np; idx += 64 * NT) {
      unsigned bits = keys[idx];
      if ((bits >> 21) == s0.bucket) atomicAdd(&lh[(bits >> 10) & 0x7FFu], 1u);
    }
    __syncthreads();
    for (int q = t; q < 2048; q += NT) {
      unsigned c = lh[q];
      if (c) atomicAdd(&h1[q], c);
    }
    return;
  }
  int pr = bid - 64;                        // 0..511, two rows each
  int half = t >> 7, c = t & 127;
  int row = 2 * pr + half;
  float m_c, s_c;
  col_ms(csum, csq, c, m_c, s_c);
  float v = (x[row * D + c] - m_c) / s_c;
  xn[row * D + c] = v;
  if (c == TDIM) z2[row] = v;
  __shared__ float red[NT];
  red[t] = (c != TDIM) ? v * v : 0.f;
  __syncthreads();
  for (int o = 64; o > 0; o >>= 1) {
    if ((t & 127) < o) red[t] += red[t + o];
    __syncthreads();
  }
  if ((t & 127) == 0) r2o[row] = red[t];
  (void)half;
}

// ---- K3: hist level 2 (stream keys via LDS hist) ----
__global__ void __launch_bounds__(NT) k3_h2(const unsigned* __restrict__ keys,
                                            const unsigned* __restrict__ cursor,
                                            const unsigned* __restrict__ h0,
                                            const unsigned* __restrict__ h1,
                                            unsigned* __restrict__ h2) {
  int bid = blockIdx.x, t = threadIdx.x;
  SelOut s0 = block_select(h0, 2048, 0xFFFFFFFFu);
  if (s0.total == 0) return;
  SelOut s1 = block_select(h1, 2048, s0.rem);
  unsigned pref = (s0.bucket << 11) | s1.bucket;
  __shared__ unsigned lh[1024];
  for (int q = t; q < 1024; q += NT) lh[q] = 0;
  __syncthreads();
  unsigned np = cursor[0];
  for (unsigned idx = bid * NT + t; idx < np; idx += 64 * NT) {
    unsigned bits = keys[idx];
    if ((bits >> 10) == pref) atomicAdd(&lh[bits & 0x3FFu], 1u);
  }
  __syncthreads();
  for (int q = t; q < 1024; q += NT) {
    unsigned c = lh[q];
    if (c) atomicAdd(&h2[q], c);
  }
}

// ---- K4: pairwise pass (redundant selects; ballot-compacted j list) ----
__global__ void __launch_bounds__(NT) k4_pair(const float* __restrict__ y,
                                              const float* __restrict__ z2,
                                              const float* __restrict__ r2o,
                                              const float* __restrict__ xn,
                                              const unsigned* __restrict__ h0,
                                              const unsigned* __restrict__ h1,
                                              const unsigned* __restrict__ h2,
                                              const u64* __restrict__ csum,
                                              const u64* __restrict__ csq,
                                              float* __restrict__ loss_i,
                                              unsigned* __restrict__ haspos_i) {
  int t = threadIdx.x;
  int i = blockIdx.x;

  SelOut s0 = block_select(h0, 2048, 0xFFFFFFFFu);
  SelOut s1; s1.bucket = 0; s1.rem = 0;
  SelOut s2; s2.bucket = 0;
  if (s0.total) {
    s1 = block_select(h1, 2048, s0.rem);
    s2 = block_select(h2, 1024, s1.rem);
  }
  __shared__ float tb;
  if (t == 0) {
    if (s0.total) {
      unsigned bits = (s0.bucket << 21) | (s1.bucket << 10) | s2.bucket;
      float mc, sc; col_ms(csum, csq, TDIM, mc, sc);
      float inv = 1.0f / sc;
      tb = fmaxf(__uint_as_float(bits) * inv * inv, 1e-6f);
    } else tb = 2.0f;
  }
  __syncthreads();
  const float invT = 1.0f / tb;

  __shared__ float xi_sh[D];
  if (t < D) xi_sh[t] = xn[i * D + t];

  float yi = y[i], zi = z2[i], ri = r2o[i];

  // den1 over ALL j (j==i contributes exp(0)=1 exactly; removed after reduce)
  float4 zz = *(const float4*)(z2 + t * 4);
  float e0 = zi - zz.x, e1 = zi - zz.y, e2 = zi - zz.z, e3 = zi - zz.w;
  float den1 = __expf(-e0 * e0 * invT) + __expf(-e1 * e1 * invT)
             + __expf(-e2 * e2 * invT) + __expf(-e3 * e3 * invT);

  // deterministic ballot-compaction of same-age neighbors
  __shared__ unsigned short jlist[B];
  __shared__ unsigned wcnt_sh[4];
  unsigned base = 0;
  int lane = t & 63, wv = t >> 6;
  for (int rnd = 0; rnd < 4; ++rnd) {
    int j = rnd * NT + t;
    bool ok = (j != i) && (fabsf(yi - y[j]) <= THR);
    unsigned long long mk = __ballot(ok);
    if (lane == 0) wcnt_sh[wv] = (unsigned)__popcll(mk);
    __syncthreads();
    unsigned pre = base;
    for (int w2 = 0; w2 < wv; ++w2) pre += wcnt_sh[w2];
    if (ok) {
      unsigned mypos = (unsigned)__popcll(mk & ((1ull << lane) - 1ull));
      jlist[pre + mypos] = (unsigned short)j;
    }
    base += wcnt_sh[0] + wcnt_sh[1] + wcnt_sh[2] + wcnt_sh[3];
    __syncthreads();
  }
  unsigned cnt = base;   // block-uniform, deterministic (sorted by j)

  float num = 0.f, den2 = 0.f;
  for (unsigned q = t; q < cnt; q += NT) {
    int j = jlist[q];
    float zj = z2[j];
    float dz = zi - zj;
    num += __expf(-dz * dz * invT);
    const float* xj = xn + j * D;
    float dot = 0.f;
#pragma unroll
    for (int d = 0; d < D; d += 4) {
      float4 a  = *(const float4*)(xi_sh + d);
      float4 bb = *(const float4*)(xj + d);
      dot += a.x * bb.x + a.y * bb.y + a.z * bb.z + a.w * bb.w;
    }
    float dot_o = dot - xi_sh[TDIM] * xj[TDIM];
    float sq = fmaxf((ri + r2o[j] - 2.f * dot_o) * (1.0f / 127.0f), 0.f);
    den2 += __expf(-sq * invT);
  }

  __shared__ float rn[NT], r1[NT], r2s[NT];
  rn[t] = num; r1[t] = den1; r2s[t] = den2;
  __syncthreads();
  for (int o = 128; o > 0; o >>= 1) {
    if (t < o) { rn[t] += rn[t + o]; r1[t] += r1[t + o]; r2s[t] += r2s[t + o]; }
    __syncthreads();
  }
  if (t == 0) {
    float den1t = r1[0] - 1.0f;               // remove j==i term
    float denom = LAM1f * den1t + LAM2f * r2s[0] + EPSf;
    float frac = fminf(fmaxf(rn[0] / denom, 1e-12f), 1.0f - 1e-7f);
    loss_i[i]   = (cnt > 0) ? -__logf(frac) : 0.f;
    haspos_i[i] = (cnt > 0) ? 1u : 0u;
  }
}

// ---- K5: final deterministic reduction to scalar loss ----
__global__ void __launch_bounds__(NT) k5_final(const float* __restrict__ loss_i,
                                               const unsigned* __restrict__ haspos_i,
                                               float* __restrict__ out) {
  __shared__ float rs[NT];
  __shared__ unsigned rcnt[NT];
  int t = threadIdx.x;
  float sv = 0.f;
  unsigned c = 0;
  for (int i = t; i < B; i += NT) { sv += loss_i[i]; c += haspos_i[i]; }
  rs[t] = sv; rcnt[t] = c;
  __syncthreads();
  for (int o = 128; o > 0; o >>= 1) {
    if (t < o) { rs[t] += rs[t + o]; rcnt[t] += rcnt[t + o]; }
    __syncthreads();
  }
  if (t == 0) out[0] = (rcnt[0] > 0) ? rs[0] / (float)rcnt[0] : 0.f;
}

extern "C" void kernel_launch(void* const* d_in, const int* in_sizes, int n_in,
                              void* d_out, int out_size, void* d_ws, size_t ws_size,
                              hipStream_t stream) {
  const float* x = (const float*)d_in[0];   // (1024,128) f32
  const float* y = (const float*)d_in[1];   // (1024,)    f32
  float* out = (float*)d_out;               // scalar f32

  char* w = (char*)d_ws;
  unsigned* zb     = (unsigned*)w;                 // zeroed region: u32[5648]
  unsigned* h0     = zb;                           // 2048
  unsigned* h1     = zb + 2048;                    // 2048
  unsigned* h2     = zb + 4096;                    // 1024
  unsigned* cursor = zb + 5120;                    // 1 (+15 pad)
  u64* csum        = (u64*)(w + 20544);            // 128 x u64
  u64* csq         = (u64*)(w + 21568);            // 128 x u64 (zero ends 22592)
  float* xcol1     = (float*)(w + 22592);          // 4 KB
  float* z2        = (float*)(w + 26688);          // 4 KB
  float* r2o       = (float*)(w + 30784);          // 4 KB
  float* loss_i    = (float*)(w + 34880);          // 4 KB
  unsigned* haspos = (unsigned*)(w + 38976);       // 4 KB
  float* xn        = (float*)(w + 43072);          // 512 KB
  unsigned* keys   = (unsigned*)(w + 567360);      // 4 MB (worst case 1024*1023)

  k0_init<<<12, NT, 0, stream>>>(x, zb, xcol1);
  k1_colsum_keys<<<64 + 256, NT, 0, stream>>>(x, y, xcol1, csum, csq,
                                              cursor, keys, h0);
  k2_h1_norm<<<64 + B / 2, NT, 0, stream>>>(x, keys, cursor, h0, h1,
                                            csum, csq, xn, z2, r2o);
  k3_h2<<<64, NT, 0, stream>>>(keys, cursor, h0, h1, h2);
  k4_pair<<<B, NT, 0, stream>>>(y, z2, r2o, xn, h0, h1, h2, csum, csq,
                                loss_i, haspos);
  k5_final<<<1, NT, 0, stream>>>(loss_i, haspos, out);
}